// Round 1
// baseline (17715.375 us; speedup 1.0000x reference)
//
#include <hip/hip_runtime.h>
#include <math.h>

// LSTM encode: B=256, T=512, FEAT=128, ACT=32 (D=160), H=512, out = h_T [256,512] f32.
// Round 0: correctness-first tiled fp32 step kernel, 512 launches (one per timestep).
// Each block: BM=16 batch rows x 32 hidden units (=128 z-cols: all 4 gates), K=672
// (x@W fused with h@U). Gate update + c/h write fused in the same kernel.

#define HIDDEN 512
#define FEATD 128
#define ACTD 32
#define DIMD 160          // FEATD + ACTD
#define GATES 2048        // 4*HIDDEN
#define BATCH 256
#define TSTEPS 512

#define BM 16             // batch tile
#define BNH 32            // hidden units per block -> 128 z columns
#define BCOLS 128
#define KT 32             // K tile
#define NKT 21            // 672 / 32  (tiles 0-3: features, 4: actions, 5-20: h)

#define PADX 18           // lds_xh leading pad (even -> aligned float2, 2-way bank max)
#define PADU 132          // lds_u row stride (multiple of 4 -> float4 aligned)

__device__ __forceinline__ float fast_sigmoid(float x) {
    return 1.0f / (1.0f + __expf(-x));
}
__device__ __forceinline__ float fast_tanh(float x) {
    // 1 - 2/(e^{2x}+1); saturates correctly at +/-inf
    return 1.0f - 2.0f / (__expf(2.0f * x) + 1.0f);
}

__launch_bounds__(256)
__global__ void lstm_step(const float* __restrict__ features,
                          const float* __restrict__ actions,
                          const float* __restrict__ Wm,
                          const float* __restrict__ Um,
                          const float* __restrict__ bias,
                          const float* __restrict__ h_in,
                          float* __restrict__ h_out,
                          float* __restrict__ c_st,
                          int t)
{
    __shared__ float lds_xh[KT * PADX];   // [kk][m] k-major
    __shared__ float lds_u [KT * PADU];   // [kk][128 cols]; reused as z-buffer in epilogue

    const int tid = threadIdx.x;
    const int b0 = blockIdx.x * BM;
    const int n0 = blockIdx.y * BNH;

    const int tn = tid & 31;   // col group: owns cols 4*tn .. 4*tn+3 (within one gate slab)
    const int tm = tid >> 5;   // m group: owns m = 2*tm, 2*tm+1

    float acc[2][4];
    #pragma unroll
    for (int i = 0; i < 2; ++i)
        #pragma unroll
        for (int j = 0; j < 4; ++j) acc[i][j] = 0.0f;

    for (int kt = 0; kt < NKT; ++kt) {
        const int k0 = kt * KT;
        __syncthreads();   // protect LDS from previous iteration's readers

        // ---- stage xh tile: 16 m x 32 k, k-major in LDS -------------------
        {
            const int kk = tid & 31;
            int m = tid >> 5;          // 0..7, then 8..15
            #pragma unroll
            for (int r = 0; r < 2; ++r, m += 8) {
                const int k = k0 + kk;
                const int b = b0 + m;
                float v;
                if (k < FEATD)
                    v = features[(size_t)b * (TSTEPS * FEATD) + (size_t)t * FEATD + k];
                else if (k < DIMD)
                    v = actions[(size_t)b * (TSTEPS * ACTD) + (size_t)t * ACTD + (k - FEATD)];
                else
                    v = h_in[b * HIDDEN + (k - DIMD)];
                lds_xh[kk * PADX + m] = v;
            }
        }
        // ---- stage W/U tile: 32 k x 128 cols (4 gate slabs of 32) ---------
        {
            const float* M = (k0 < DIMD) ? Wm : Um;
            const int krow0 = (k0 < DIMD) ? k0 : (k0 - DIMD);
            #pragma unroll
            for (int r = 0; r < 4; ++r) {
                const int id = tid + 256 * r;        // 0..1023 float4s
                const int j4 = id & 7;
                const int gr = (id >> 3) & 3;
                const int kk = id >> 5;
                const float4 v = *(const float4*)&M[(size_t)(krow0 + kk) * GATES
                                                   + gr * HIDDEN + n0 + j4 * 4];
                *(float4*)&lds_u[kk * PADU + gr * 32 + j4 * 4] = v;
            }
        }
        __syncthreads();

        // ---- inner product over this K tile -------------------------------
        #pragma unroll
        for (int kk = 0; kk < KT; ++kk) {
            const float x0 = lds_xh[kk * PADX + 2 * tm];
            const float x1 = lds_xh[kk * PADX + 2 * tm + 1];
            const float4 u = *(const float4*)&lds_u[kk * PADU + 4 * tn];
            acc[0][0] += x0 * u.x; acc[0][1] += x0 * u.y;
            acc[0][2] += x0 * u.z; acc[0][3] += x0 * u.w;
            acc[1][0] += x1 * u.x; acc[1][1] += x1 * u.y;
            acc[1][2] += x1 * u.z; acc[1][3] += x1 * u.w;
        }
    }

    // ---- epilogue: z -> LDS, then gate fusion -----------------------------
    __syncthreads();
    #pragma unroll
    for (int mi = 0; mi < 2; ++mi) {
        const int m = tm * 2 + mi;
        *(float4*)&lds_u[m * PADU + 4 * tn] = *(float4*)&acc[mi][0];
    }
    __syncthreads();

    #pragma unroll
    for (int r = 0; r < 2; ++r) {
        const int p = tid + 256 * r;      // 0..511 (m, unit) pairs
        const int j = p & 31;             // unit within block
        const int m = p >> 5;             // batch row within tile
        const float zi = lds_u[m * PADU +  0 + j] + bias[0 * HIDDEN + n0 + j];
        const float zf = lds_u[m * PADU + 32 + j] + bias[1 * HIDDEN + n0 + j];
        const float zg = lds_u[m * PADU + 64 + j] + bias[2 * HIDDEN + n0 + j];
        const float zo = lds_u[m * PADU + 96 + j] + bias[3 * HIDDEN + n0 + j];
        const float ig = fast_sigmoid(zi);
        const float fg = fast_sigmoid(zf);
        const float gg = fast_tanh(zg);
        const float og = fast_sigmoid(zo);
        const size_t idx = (size_t)(b0 + m) * HIDDEN + n0 + j;
        const float c_new = fg * c_st[idx] + ig * gg;
        c_st[idx] = c_new;
        h_out[idx] = og * fast_tanh(c_new);
    }
}

extern "C" void kernel_launch(void* const* d_in, const int* in_sizes, int n_in,
                              void* d_out, int out_size, void* d_ws, size_t ws_size,
                              hipStream_t stream) {
    const float* features = (const float*)d_in[0];
    const float* actions  = (const float*)d_in[1];
    const float* Wm       = (const float*)d_in[2];
    const float* Um       = (const float*)d_in[3];
    const float* bias     = (const float*)d_in[4];
    float* out = (float*)d_out;

    float* h0 = (float*)d_ws;                       // 256*512 f32
    float* h1 = h0 + BATCH * HIDDEN;
    float* c  = h1 + BATCH * HIDDEN;

    // zero h0, h1, c (ws is poisoned 0xAA before every timed call)
    hipMemsetAsync(d_ws, 0, (size_t)3 * BATCH * HIDDEN * sizeof(float), stream);

    dim3 grid(BATCH / BM, HIDDEN / BNH);            // 16 x 16 = 256 blocks
    for (int t = 0; t < TSTEPS; ++t) {
        const float* hin = (t & 1) ? h1 : h0;
        float* hout = (t == TSTEPS - 1) ? out : ((t & 1) ? h0 : h1);
        lstm_step<<<grid, 256, 0, stream>>>(features, actions, Wm, Um, bias,
                                            hin, hout, c, t);
    }
}

// Round 3
// 9620.259 us; speedup vs baseline: 1.8415x; 1.8415x over previous
//
#include <hip/hip_runtime.h>
#include <math.h>

// LSTM encode, round 2 (resubmit after infra timeout): bf16x3 split-precision
// MFMA step kernel. z = [x|h] @ [W;U] computed as ahi*Bhi + alo*Bhi + ahi*Blo
// (fp32 accum) -> ~fp32 accuracy with MFMA throughput. Barrier-free, LDS-free
// step kernel: 256 blocks x 64 threads (1 wave), each wave owns a 32x64 output
// tile (32 batch rows x 16 units x 4 gates), K=672 fused (x:160 + h:512).
// Weights pre-packed into MFMA B-fragment order (hi/lo bf16) once per call.

#define HIDDEN 512
#define TSTEPS 512
#define BATCH 256
#define FEATD 128
#define ACTD 32
#define DIMD 160
#define GATES 2048
#define NKT 21              // 672 / 32 k-tiles (0-3 feat, 4 act, 5-20 h)
#define NGROUPS 32          // 2048 packed cols / 64
#define NFRAGS (NGROUPS * NKT * 4)   // 2688 B-fragments (each 64 lanes x 8 bf16)

typedef short bf16x8 __attribute__((ext_vector_type(8)));
typedef float f32x4 __attribute__((ext_vector_type(4)));

__device__ __forceinline__ unsigned short f2bf(float v) {
    union { float f; unsigned u; } c; c.f = v;
    unsigned r = c.u + 0x7fffu + ((c.u >> 16) & 1u);   // RNE
    return (unsigned short)(r >> 16);
}
__device__ __forceinline__ float bf2f(unsigned short s) {
    union { unsigned u; float f; } c; c.u = ((unsigned)s) << 16; return c.f;
}
__device__ __forceinline__ float fast_sigmoid(float x) {
    return 1.0f / (1.0f + __expf(-x));
}
__device__ __forceinline__ float fast_tanh(float x) {
    return 1.0f - 2.0f / (__expf(2.0f * x) + 1.0f);
}

// ---- pack [W;U] (672 x 2048 fp32) into B-fragment-ordered hi/lo bf16 -------
// frag f = (ng*NKT + kt)*4 + tc; element (lane,j) = B[k][col],
// k = kt*32 + (lane>>4)*8 + j, col = tc*512 + ng*16 + (lane&15).
// Same (lane,j)->k map as the A fragments, so any error in the assumed
// within-lane k order cancels between A and B.
__global__ __launch_bounds__(256)
void pack_weights(const float* __restrict__ W, const float* __restrict__ U,
                  unsigned short* __restrict__ Bhi, unsigned short* __restrict__ Blo)
{
    const int idx = blockIdx.x * 256 + threadIdx.x;     // (f, lane) pairs
    if (idx >= NFRAGS * 64) return;
    const int lane = idx & 63;
    const int f = idx >> 6;
    const int tc = f & 3;
    const int kt = (f >> 2) % NKT;
    const int ng = (f >> 2) / NKT;
    const int col = tc * HIDDEN + ng * 16 + (lane & 15);
    const int kbase = kt * 32 + (lane >> 4) * 8;
    #pragma unroll
    for (int j = 0; j < 8; ++j) {
        const int k = kbase + j;
        const float v = (k < DIMD) ? W[(size_t)k * GATES + col]
                                   : U[(size_t)(k - DIMD) * GATES + col];
        const unsigned short hi = f2bf(v);
        Bhi[(size_t)idx * 8 + j] = hi;
        Blo[(size_t)idx * 8 + j] = f2bf(v - bf2f(hi));
    }
}

// ---- one LSTM timestep -----------------------------------------------------
__global__ __launch_bounds__(64)
void lstm_step_mfma(const float* __restrict__ feat, const float* __restrict__ act,
                    const unsigned short* __restrict__ Bhi,
                    const unsigned short* __restrict__ Blo,
                    const float* __restrict__ bias,
                    const unsigned short* __restrict__ hin_hi,
                    const unsigned short* __restrict__ hin_lo,
                    unsigned short* __restrict__ hout_hi,
                    unsigned short* __restrict__ hout_lo,
                    float* __restrict__ c_st, float* __restrict__ out,
                    int t, int last)
{
    const int lane = threadIdx.x;
    const int ng = blockIdx.x;          // 0..31  (x-fastest -> XCD partitions N)
    const int mb = blockIdx.y;          // 0..7
    const int m0 = mb * 32;
    const int u0 = ng * 16;
    const int kg = lane >> 4;           // k-group (A and B)
    const int nn = lane & 15;           // A row within 16-group / B col

    f32x4 acc[2][4];
    #pragma unroll
    for (int mg = 0; mg < 2; ++mg)
        #pragma unroll
        for (int tc = 0; tc < 4; ++tc)
            acc[mg][tc] = (f32x4){0.f, 0.f, 0.f, 0.f};

    // ---- x tiles (kt 0..4): load fp32, split to hi/lo on the fly ----------
    #pragma unroll
    for (int kt = 0; kt < 5; ++kt) {
        bf16x8 ahi[2], alo[2];
        #pragma unroll
        for (int mg = 0; mg < 2; ++mg) {
            const int b = m0 + mg * 16 + nn;
            const float* src = (kt < 4)
                ? feat + ((size_t)b * TSTEPS + t) * FEATD + kt * 32 + kg * 8
                : act  + ((size_t)b * TSTEPS + t) * ACTD  + kg * 8;
            const float4 v0 = *(const float4*)src;
            const float4 v1 = *(const float4*)(src + 4);
            const float vv[8] = {v0.x, v0.y, v0.z, v0.w, v1.x, v1.y, v1.z, v1.w};
            #pragma unroll
            for (int j = 0; j < 8; ++j) {
                const unsigned short h = f2bf(vv[j]);
                ahi[mg][j] = (short)h;
                alo[mg][j] = (short)f2bf(vv[j] - bf2f(h));
            }
        }
        const unsigned short* bh = Bhi + (size_t)(ng * NKT + kt) * 4 * 512 + lane * 8;
        const unsigned short* bl = Blo + (size_t)(ng * NKT + kt) * 4 * 512 + lane * 8;
        #pragma unroll
        for (int tc = 0; tc < 4; ++tc) {
            const bf16x8 bhv = *(const bf16x8*)(bh + tc * 512);
            const bf16x8 blv = *(const bf16x8*)(bl + tc * 512);
            #pragma unroll
            for (int mg = 0; mg < 2; ++mg) {
                acc[mg][tc] = __builtin_amdgcn_mfma_f32_16x16x32_bf16(ahi[mg], bhv, acc[mg][tc], 0, 0, 0);
                acc[mg][tc] = __builtin_amdgcn_mfma_f32_16x16x32_bf16(alo[mg], bhv, acc[mg][tc], 0, 0, 0);
                acc[mg][tc] = __builtin_amdgcn_mfma_f32_16x16x32_bf16(ahi[mg], blv, acc[mg][tc], 0, 0, 0);
            }
        }
    }

    // ---- h tiles (kt 5..20): h already stored as hi/lo bf16 ----------------
    #pragma unroll 4
    for (int kt = 5; kt < NKT; ++kt) {
        const int hk = kt * 32 - DIMD + kg * 8;
        bf16x8 ahi[2], alo[2];
        #pragma unroll
        for (int mg = 0; mg < 2; ++mg) {
            const int b = m0 + mg * 16 + nn;
            ahi[mg] = *(const bf16x8*)(hin_hi + (size_t)b * HIDDEN + hk);
            alo[mg] = *(const bf16x8*)(hin_lo + (size_t)b * HIDDEN + hk);
        }
        const unsigned short* bh = Bhi + (size_t)(ng * NKT + kt) * 4 * 512 + lane * 8;
        const unsigned short* bl = Blo + (size_t)(ng * NKT + kt) * 4 * 512 + lane * 8;
        #pragma unroll
        for (int tc = 0; tc < 4; ++tc) {
            const bf16x8 bhv = *(const bf16x8*)(bh + tc * 512);
            const bf16x8 blv = *(const bf16x8*)(bl + tc * 512);
            #pragma unroll
            for (int mg = 0; mg < 2; ++mg) {
                acc[mg][tc] = __builtin_amdgcn_mfma_f32_16x16x32_bf16(ahi[mg], bhv, acc[mg][tc], 0, 0, 0);
                acc[mg][tc] = __builtin_amdgcn_mfma_f32_16x16x32_bf16(alo[mg], bhv, acc[mg][tc], 0, 0, 0);
                acc[mg][tc] = __builtin_amdgcn_mfma_f32_16x16x32_bf16(ahi[mg], blv, acc[mg][tc], 0, 0, 0);
            }
        }
    }

    // ---- epilogue: gates + c/h update; lane+reg owns one (b,u) fully -------
    const float bi = bias[0 * HIDDEN + u0 + nn];
    const float bf_ = bias[1 * HIDDEN + u0 + nn];
    const float bg = bias[2 * HIDDEN + u0 + nn];
    const float bo = bias[3 * HIDDEN + u0 + nn];
    #pragma unroll
    for (int mg = 0; mg < 2; ++mg) {
        #pragma unroll
        for (int r = 0; r < 4; ++r) {
            const int b = m0 + mg * 16 + kg * 4 + r;   // C/D row = (lane>>4)*4+reg
            const size_t idx = (size_t)b * HIDDEN + u0 + nn;
            const float ig = fast_sigmoid(acc[mg][0][r] + bi);
            const float fg = fast_sigmoid(acc[mg][1][r] + bf_);
            const float gg = fast_tanh   (acc[mg][2][r] + bg);
            const float og = fast_sigmoid(acc[mg][3][r] + bo);
            const float cn = fg * c_st[idx] + ig * gg;
            c_st[idx] = cn;
            const float hv = og * fast_tanh(cn);
            const unsigned short hh = f2bf(hv);
            hout_hi[idx] = hh;
            hout_lo[idx] = f2bf(hv - bf2f(hh));
            if (last) out[idx] = hv;
        }
    }
}

extern "C" void kernel_launch(void* const* d_in, const int* in_sizes, int n_in,
                              void* d_out, int out_size, void* d_ws, size_t ws_size,
                              hipStream_t stream) {
    const float* features = (const float*)d_in[0];
    const float* actions  = (const float*)d_in[1];
    const float* W        = (const float*)d_in[2];
    const float* U        = (const float*)d_in[3];
    const float* bias     = (const float*)d_in[4];
    float* out = (float*)d_out;

    const size_t HB = (size_t)BATCH * HIDDEN;          // 131072
    unsigned short* h_hi0 = (unsigned short*)d_ws;
    unsigned short* h_lo0 = h_hi0 + HB;
    unsigned short* h_hi1 = h_lo0 + HB;
    unsigned short* h_lo1 = h_hi1 + HB;
    float* c_st = (float*)(h_lo1 + HB);
    unsigned short* Bhi = (unsigned short*)(c_st + HB);
    unsigned short* Blo = Bhi + (size_t)NFRAGS * 512;  // 2688*512 elems each

    // zero h ping/pong (hi/lo) + c: 4*2B*HB + 4B*HB = 12B * HB
    hipMemsetAsync(d_ws, 0, HB * 12, stream);
    pack_weights<<<(NFRAGS * 64 + 255) / 256, 256, 0, stream>>>(W, U, Bhi, Blo);

    dim3 grid(NGROUPS, BATCH / 32);                    // 32 x 8 = 256 one-wave blocks
    for (int t = 0; t < TSTEPS; ++t) {
        const unsigned short* hih = (t & 1) ? h_hi1 : h_hi0;
        const unsigned short* hil = (t & 1) ? h_lo1 : h_lo0;
        unsigned short* hoh = (t & 1) ? h_hi0 : h_hi1;
        unsigned short* hol = (t & 1) ? h_lo0 : h_lo1;
        lstm_step_mfma<<<grid, 64, 0, stream>>>(features, actions, Bhi, Blo, bias,
                                                hih, hil, hoh, hol, c_st, out,
                                                t, t == TSTEPS - 1);
    }
}

// Round 4
// 4861.182 us; speedup vs baseline: 3.6443x; 1.9790x over previous
//
#include <hip/hip_runtime.h>
#include <math.h>

// LSTM encode, round 4: bf16x3 split MFMA + 4-wave K-split blocks.
// 256 blocks (1/CU), 256 threads = 4 waves. Block computes a 32b x 64pc tile
// (16 units x 4 gates). Wave w sums a K-range (w0: x kt0-4 + h kt5; w1-3: 5 h
// tiles each); partials reduced via LDS; 256-thread gate epilogue.

#define HIDDEN 512
#define TSTEPS 512
#define BATCH 256
#define FEATD 128
#define ACTD 32
#define DIMD 160
#define GATES 2048
#define NKT 21
#define NGROUPS 32
#define NFRAGS (NGROUPS * NKT * 4)

#define SB 74                 // zbuf stride per b-row (f32), even + conflict-light
#define SW (32 * SB)          // zbuf stride per wave = 2368

typedef short bf16x8 __attribute__((ext_vector_type(8)));
typedef float f32x4 __attribute__((ext_vector_type(4)));

__device__ __forceinline__ unsigned short f2bf(float v) {
    union { float f; unsigned u; } c; c.f = v;
    unsigned r = c.u + 0x7fffu + ((c.u >> 16) & 1u);
    return (unsigned short)(r >> 16);
}
__device__ __forceinline__ float bf2f(unsigned short s) {
    union { unsigned u; float f; } c; c.u = ((unsigned)s) << 16; return c.f;
}
__device__ __forceinline__ float fast_sigmoid(float x) {
    return 1.0f / (1.0f + __expf(-x));
}
__device__ __forceinline__ float fast_tanh(float x) {
    return 1.0f - 2.0f / (__expf(2.0f * x) + 1.0f);
}

// ---- pack [W;U] (672 x 2048 fp32) into B-fragment-ordered hi/lo bf16 -------
// frag f = (ng*NKT + kt)*4 + tc; element (lane,j) = B[k][col],
// k = kt*32 + (lane>>4)*8 + j, col = tc*512 + ng*16 + (lane&15).
__global__ __launch_bounds__(256)
void pack_weights(const float* __restrict__ W, const float* __restrict__ U,
                  unsigned short* __restrict__ Bhi, unsigned short* __restrict__ Blo)
{
    const int idx = blockIdx.x * 256 + threadIdx.x;
    if (idx >= NFRAGS * 64) return;
    const int lane = idx & 63;
    const int f = idx >> 6;
    const int tc = f & 3;
    const int kt = (f >> 2) % NKT;
    const int ng = (f >> 2) / NKT;
    const int col = tc * HIDDEN + ng * 16 + (lane & 15);
    const int kbase = kt * 32 + (lane >> 4) * 8;
    #pragma unroll
    for (int j = 0; j < 8; ++j) {
        const int k = kbase + j;
        const float v = (k < DIMD) ? W[(size_t)k * GATES + col]
                                   : U[(size_t)(k - DIMD) * GATES + col];
        const unsigned short hi = f2bf(v);
        Bhi[(size_t)idx * 8 + j] = hi;
        Blo[(size_t)idx * 8 + j] = f2bf(v - bf2f(hi));
    }
}

__device__ __forceinline__ void mfma_tile(const bf16x8* ahi, const bf16x8* alo,
                                          const unsigned short* bh,
                                          const unsigned short* bl,
                                          f32x4 (&acc)[2][4])
{
    #pragma unroll
    for (int tc = 0; tc < 4; ++tc) {
        const bf16x8 bhv = *(const bf16x8*)(bh + tc * 512);
        const bf16x8 blv = *(const bf16x8*)(bl + tc * 512);
        #pragma unroll
        for (int mg = 0; mg < 2; ++mg) {
            acc[mg][tc] = __builtin_amdgcn_mfma_f32_16x16x32_bf16(ahi[mg], bhv, acc[mg][tc], 0, 0, 0);
            acc[mg][tc] = __builtin_amdgcn_mfma_f32_16x16x32_bf16(alo[mg], bhv, acc[mg][tc], 0, 0, 0);
            acc[mg][tc] = __builtin_amdgcn_mfma_f32_16x16x32_bf16(ahi[mg], blv, acc[mg][tc], 0, 0, 0);
        }
    }
}

__global__ __launch_bounds__(256)
void lstm_step_mfma(const float* __restrict__ feat, const float* __restrict__ act,
                    const unsigned short* __restrict__ Bhi,
                    const unsigned short* __restrict__ Blo,
                    const float* __restrict__ bias,
                    const unsigned short* __restrict__ hin_hi,
                    const unsigned short* __restrict__ hin_lo,
                    unsigned short* __restrict__ hout_hi,
                    unsigned short* __restrict__ hout_lo,
                    float* __restrict__ c_st, float* __restrict__ out,
                    int t, int last)
{
    __shared__ float zbuf[4 * SW];    // 37,888 B

    const int tid = threadIdx.x;
    const int lane = tid & 63;
    const int w = tid >> 6;
    const int ng = blockIdx.x;        // x-fastest -> XCD gets ng%8 slice of weights
    const int mb = blockIdx.y;
    const int m0 = mb * 32;
    const int u0 = ng * 16;
    const int kg = lane >> 4;
    const int nn = lane & 15;

    f32x4 acc[2][4];
    #pragma unroll
    for (int mg = 0; mg < 2; ++mg)
        #pragma unroll
        for (int tc = 0; tc < 4; ++tc)
            acc[mg][tc] = (f32x4){0.f, 0.f, 0.f, 0.f};

    if (w == 0) {
        // ---- x tiles (kt 0..4): fp32 load, split hi/lo on the fly ---------
        #pragma unroll
        for (int kt = 0; kt < 5; ++kt) {
            bf16x8 ahi[2], alo[2];
            #pragma unroll
            for (int mg = 0; mg < 2; ++mg) {
                const int b = m0 + mg * 16 + nn;
                const float* src = (kt < 4)
                    ? feat + ((size_t)b * TSTEPS + t) * FEATD + kt * 32 + kg * 8
                    : act  + ((size_t)b * TSTEPS + t) * ACTD  + kg * 8;
                const float4 v0 = *(const float4*)src;
                const float4 v1 = *(const float4*)(src + 4);
                const float vv[8] = {v0.x, v0.y, v0.z, v0.w, v1.x, v1.y, v1.z, v1.w};
                #pragma unroll
                for (int j = 0; j < 8; ++j) {
                    const unsigned short h = f2bf(vv[j]);
                    ahi[mg][j] = (short)h;
                    alo[mg][j] = (short)f2bf(vv[j] - bf2f(h));
                }
            }
            const unsigned short* bh = Bhi + (size_t)(ng * NKT + kt) * 2048 + lane * 8;
            const unsigned short* bl = Blo + (size_t)(ng * NKT + kt) * 2048 + lane * 8;
            mfma_tile(ahi, alo, bh, bl, acc);
        }
        // ---- h tile kt = 5 -------------------------------------------------
        {
            const int hk = 0 + kg * 8;
            bf16x8 ahi[2], alo[2];
            #pragma unroll
            for (int mg = 0; mg < 2; ++mg) {
                const int b = m0 + mg * 16 + nn;
                ahi[mg] = *(const bf16x8*)(hin_hi + (size_t)b * HIDDEN + hk);
                alo[mg] = *(const bf16x8*)(hin_lo + (size_t)b * HIDDEN + hk);
            }
            const unsigned short* bh = Bhi + (size_t)(ng * NKT + 5) * 2048 + lane * 8;
            const unsigned short* bl = Blo + (size_t)(ng * NKT + 5) * 2048 + lane * 8;
            mfma_tile(ahi, alo, bh, bl, acc);
        }
    } else {
        const int kt0 = 1 + w * 5;    // w1:6..10  w2:11..15  w3:16..20
        #pragma unroll
        for (int i = 0; i < 5; ++i) {
            const int kt = kt0 + i;
            const int hk = kt * 32 - DIMD + kg * 8;
            bf16x8 ahi[2], alo[2];
            #pragma unroll
            for (int mg = 0; mg < 2; ++mg) {
                const int b = m0 + mg * 16 + nn;
                ahi[mg] = *(const bf16x8*)(hin_hi + (size_t)b * HIDDEN + hk);
                alo[mg] = *(const bf16x8*)(hin_lo + (size_t)b * HIDDEN + hk);
            }
            const unsigned short* bh = Bhi + (size_t)(ng * NKT + kt) * 2048 + lane * 8;
            const unsigned short* bl = Blo + (size_t)(ng * NKT + kt) * 2048 + lane * 8;
            mfma_tile(ahi, alo, bh, bl, acc);
        }
    }

    // ---- write partials to LDS --------------------------------------------
    #pragma unroll
    for (int mg = 0; mg < 2; ++mg)
        #pragma unroll
        for (int tc = 0; tc < 4; ++tc)
            #pragma unroll
            for (int r = 0; r < 4; ++r)
                zbuf[w * SW + (mg * 16 + kg * 4 + r) * SB + tc * 16 + nn] = acc[mg][tc][r];
    __syncthreads();

    // ---- reduce + gate epilogue: thread -> (b_local, n0..n0+1) ------------
    const int bl_ = tid >> 3;          // 0..31
    const int n0 = (tid & 7) * 2;      // 0,2,..,14
    float zg_[4][2];
    #pragma unroll
    for (int g = 0; g < 4; ++g) {
        float2 s = {0.f, 0.f};
        #pragma unroll
        for (int ww = 0; ww < 4; ++ww) {
            const float2 v = *(const float2*)&zbuf[ww * SW + bl_ * SB + g * 16 + n0];
            s.x += v.x; s.y += v.y;
        }
        zg_[g][0] = s.x; zg_[g][1] = s.y;
    }

    const int u = u0 + n0;
    const size_t idx = (size_t)(m0 + bl_) * HIDDEN + u;
    const float2 cold = *(const float2*)&c_st[idx];
    float hv[2], cn[2];
    #pragma unroll
    for (int p = 0; p < 2; ++p) {
        const float ig = fast_sigmoid(zg_[0][p] + bias[0 * HIDDEN + u + p]);
        const float fg = fast_sigmoid(zg_[1][p] + bias[1 * HIDDEN + u + p]);
        const float gg = fast_tanh   (zg_[2][p] + bias[2 * HIDDEN + u + p]);
        const float og = fast_sigmoid(zg_[3][p] + bias[3 * HIDDEN + u + p]);
        cn[p] = fg * ((p == 0) ? cold.x : cold.y) + ig * gg;
        hv[p] = og * fast_tanh(cn[p]);
    }
    *(float2*)&c_st[idx] = (float2){cn[0], cn[1]};
    const unsigned short h0 = f2bf(hv[0]), h1 = f2bf(hv[1]);
    *(unsigned*)&hout_hi[idx] = (unsigned)h0 | ((unsigned)h1 << 16);
    const unsigned short l0 = f2bf(hv[0] - bf2f(h0)), l1 = f2bf(hv[1] - bf2f(h1));
    *(unsigned*)&hout_lo[idx] = (unsigned)l0 | ((unsigned)l1 << 16);
    if (last) *(float2*)&out[idx] = (float2){hv[0], hv[1]};
}

extern "C" void kernel_launch(void* const* d_in, const int* in_sizes, int n_in,
                              void* d_out, int out_size, void* d_ws, size_t ws_size,
                              hipStream_t stream) {
    const float* features = (const float*)d_in[0];
    const float* actions  = (const float*)d_in[1];
    const float* W        = (const float*)d_in[2];
    const float* U        = (const float*)d_in[3];
    const float* bias     = (const float*)d_in[4];
    float* out = (float*)d_out;

    const size_t HB = (size_t)BATCH * HIDDEN;
    unsigned short* h_hi0 = (unsigned short*)d_ws;
    unsigned short* h_lo0 = h_hi0 + HB;
    unsigned short* h_hi1 = h_lo0 + HB;
    unsigned short* h_lo1 = h_hi1 + HB;
    float* c_st = (float*)(h_lo1 + HB);
    unsigned short* Bhi = (unsigned short*)(c_st + HB);
    unsigned short* Blo = Bhi + (size_t)NFRAGS * 512;

    hipMemsetAsync(d_ws, 0, HB * 12, stream);
    pack_weights<<<(NFRAGS * 64 + 255) / 256, 256, 0, stream>>>(W, U, Bhi, Blo);

    dim3 grid(NGROUPS, BATCH / 32);                  // 32 x 8 = 256 blocks, 1/CU
    for (int t = 0; t < TSTEPS; ++t) {
        const unsigned short* hih = (t & 1) ? h_hi1 : h_hi0;
        const unsigned short* hil = (t & 1) ? h_lo1 : h_lo0;
        unsigned short* hoh = (t & 1) ? h_hi0 : h_hi1;
        unsigned short* hol = (t & 1) ? h_lo0 : h_lo1;
        lstm_step_mfma<<<grid, 256, 0, stream>>>(features, actions, Bhi, Blo, bias,
                                                 hih, hil, hoh, hol, c_st, out,
                                                 t, t == TSTEPS - 1);
    }
}